// Round 1
// 727.918 us; speedup vs baseline: 1.3433x; 1.3433x over previous
//
#include <hip/hip_runtime.h>
#include <math.h>

// NSMCell: N=50000, E=800000, H=128, P=8, B=512
#define H_DIM 128
#define NPROP 8
#define NGRAPHS 512
#define LDS_STRIDE 136  // 128 ushorts + 8 pad -> 272B rows; A-frag ds_read_b128 lands at <=2-way (free)

typedef short short8 __attribute__((ext_vector_type(8)));
typedef float f32x4 __attribute__((ext_vector_type(4)));
typedef unsigned short ushort_t;

// split fp32 -> bf16 hi + bf16 lo (hi truncated, lo rounded): ~17-bit effective mantissa
__device__ __forceinline__ void split_bf16(float x, ushort_t& hb, ushort_t& lb) {
  unsigned u = __float_as_uint(x);
  hb = (ushort_t)(u >> 16);
  float hf = __uint_as_float(u & 0xFFFF0000u);
  float lf = x - hf;
  unsigned ul = __float_as_uint(lf);
  lb = (ushort_t)((ul + 0x8000u) >> 16);
}

__device__ __forceinline__ void split8(const float4 u, const float4 v,
                                       short8& h, short8& l) {
  ushort_t* hp = (ushort_t*)&h;
  ushort_t* lp = (ushort_t*)&l;
  split_bf16(u.x, hp[0], lp[0]);
  split_bf16(u.y, hp[1], lp[1]);
  split_bf16(u.z, hp[2], lp[2]);
  split_bf16(u.w, hp[3], lp[3]);
  split_bf16(v.x, hp[4], lp[4]);
  split_bf16(v.y, hp[5], lp[5]);
  split_bf16(v.z, hp[6], lp[6]);
  split_bf16(v.w, hp[7], lp[7]);
}

__device__ __forceinline__ float elu_f(float y) {
  return y > 0.f ? y : (__expf(y) - 1.f);
}

// ---------------------------------------------------------------------------
// prop_sim = softmax(prop_embeds @ instruction)
__global__ void prep_prop_sim(const float* __restrict__ prop_embeds,
                              const float* __restrict__ instruction,
                              float* __restrict__ prop_sim) {
  __shared__ float dots[NPROP];
  int wave = threadIdx.x >> 6;
  int lane = threadIdx.x & 63;
  float v = prop_embeds[wave * H_DIM + lane] * instruction[lane] +
            prop_embeds[wave * H_DIM + 64 + lane] * instruction[64 + lane];
#pragma unroll
  for (int off = 32; off > 0; off >>= 1) v += __shfl_down(v, off);
  if (lane == 0) dots[wave] = v;
  __syncthreads();
  if (threadIdx.x == 0) {
    float m = dots[0];
    for (int p = 1; p < NPROP; ++p) m = fmaxf(m, dots[p]);
    float e[NPROP], s = 0.f;
    for (int p = 0; p < NPROP; ++p) { e[p] = expf(dots[p] - m); s += e[p]; }
    for (int p = 0; p < NPROP; ++p) prop_sim[p] = e[p] / s;
  }
}

// ---------------------------------------------------------------------------
// Fold prop_sim[p]*instruction[h] into weights; emit bf16 hi/lo split.
__global__ void prep_weights(const float* __restrict__ Ws,
                             const float* __restrict__ instruction,
                             const float* __restrict__ prop_sim,
                             ushort_t* __restrict__ Wh,
                             ushort_t* __restrict__ Wl) {
  int idx = blockIdx.x * 256 + threadIdx.x;  // < 131072
  int p = idx >> 14;
  int h = (idx >> 7) & 127;
  float s = (p < 7) ? prop_sim[p] : 1.0f;
  float w = s * instruction[h] * Ws[idx];
  ushort_t hb, lb;
  split_bf16(w, hb, lb);
  Wh[idx] = hb;
  Wl[idx] = lb;
}

// ---------------------------------------------------------------------------
// Fused GEMM kernel.
//   blockIdx.x <  nodeBlocks : node path  (K=896 over 7 phases, restage weights)
//   blockIdx.x >= nodeBlocks : edge path  (K=128, single weight slab p=7)
// Weights live in LDS (4x reuse/block); X is loaded global->VGPR in fragment
// layout (each element consumed once), software-pipelined one K-slice ahead.
__global__ void __launch_bounds__(256) fused_mfma_kernel(
    const float* __restrict__ node_attrs,   // [N][7][128]
    const float* __restrict__ edge_attrs,   // [E][128]
    const ushort_t* __restrict__ Wh,        // [8][128][128] scaled
    const ushort_t* __restrict__ Wl,
    const float* __restrict__ W_state,      // [128]
    const float* __restrict__ W_relation,   // [128]
    const float* __restrict__ distribution, // [N]
    const int* __restrict__ src_idx,        // [E]
    const int* __restrict__ dst_idx,        // [E]
    float* __restrict__ state_logits,       // [N]
    float* __restrict__ rel_logits,         // [N] zero-init
    int N, int nodeBlocks) {
  __shared__ __align__(16) ushort_t Ah[128 * LDS_STRIDE];
  __shared__ __align__(16) ushort_t Al[128 * LDS_STRIDE];
  const int t = threadIdx.x;
  const int lane = t & 63;
  const int wave = t >> 6;
  const int col = lane & 15;
  const int quad = lane >> 4;
  const int r0 = wave * 32 + col;   // local B-row (edge/node) this lane feeds
  const int kq = quad * 8;          // k offset within a 32-wide K slice

  f32x4 acc[8][2];
#pragma unroll
  for (int m = 0; m < 8; ++m) {
    acc[m][0] = (f32x4){0.f, 0.f, 0.f, 0.f};
    acc[m][1] = (f32x4){0.f, 0.f, 0.f, 0.f};
  }

  if (blockIdx.x >= nodeBlocks) {
    // ------------------------------ edge path ------------------------------
    const long tile = (long)(blockIdx.x - nodeBlocks) * 128;
    const float* X0 = edge_attrs + (tile + r0) * H_DIM;
    const float* X1 = X0 + 16 * H_DIM;

    // issue ks=0 X loads before weight staging so they overlap it
    float4 ca0 = *(const float4*)(X0 + kq);
    float4 ca1 = *(const float4*)(X0 + kq + 4);
    float4 cb0 = *(const float4*)(X1 + kq);
    float4 cb1 = *(const float4*)(X1 + kq + 4);

    {  // stage p=7 weight slab (32KB hi + 32KB lo) into LDS
      const ushort_t* Wp_h = Wh + 7 * (H_DIM * H_DIM);
      const ushort_t* Wp_l = Wl + 7 * (H_DIM * H_DIM);
#pragma unroll
      for (int i = 0; i < 8; ++i) {
        int f = i * 256 + t;       // [0,2048): 8-ushort chunks
        int row = f >> 4;
        int c8 = (f & 15) * 8;
        *(short8*)&Ah[row * LDS_STRIDE + c8] = *(const short8*)&Wp_h[row * H_DIM + c8];
        *(short8*)&Al[row * LDS_STRIDE + c8] = *(const short8*)&Wp_l[row * H_DIM + c8];
      }
    }
    __syncthreads();

#pragma unroll
    for (int ks = 0; ks < 4; ++ks) {
      float4 na0 = ca0, na1 = ca1, nb0 = cb0, nb1 = cb1;
      if (ks < 3) {  // prefetch next K slice
        int ko = (ks + 1) * 32 + kq;
        na0 = *(const float4*)(X0 + ko);
        na1 = *(const float4*)(X0 + ko + 4);
        nb0 = *(const float4*)(X1 + ko);
        nb1 = *(const float4*)(X1 + ko + 4);
      }
      short8 b0h, b0l, b1h, b1l;
      split8(ca0, ca1, b0h, b0l);
      split8(cb0, cb1, b1h, b1l);
      const int kk = ks * 32 + kq;
#pragma unroll
      for (int m = 0; m < 8; ++m) {
        const int wi = (m * 16 + col) * LDS_STRIDE + kk;
        short8 ah = *(const short8*)&Ah[wi];
        short8 al = *(const short8*)&Al[wi];
        acc[m][0] = __builtin_amdgcn_mfma_f32_16x16x32_bf16(ah, b0h, acc[m][0], 0, 0, 0);
        acc[m][0] = __builtin_amdgcn_mfma_f32_16x16x32_bf16(ah, b0l, acc[m][0], 0, 0, 0);
        acc[m][0] = __builtin_amdgcn_mfma_f32_16x16x32_bf16(al, b0h, acc[m][0], 0, 0, 0);
        acc[m][1] = __builtin_amdgcn_mfma_f32_16x16x32_bf16(ah, b1h, acc[m][1], 0, 0, 0);
        acc[m][1] = __builtin_amdgcn_mfma_f32_16x16x32_bf16(ah, b1l, acc[m][1], 0, 0, 0);
        acc[m][1] = __builtin_amdgcn_mfma_f32_16x16x32_bf16(al, b1h, acc[m][1], 0, 0, 0);
      }
      ca0 = na0; ca1 = na1; cb0 = nb0; cb1 = nb1;
    }

    // epilogue: s_e = sum_h W_rel[h]*elu(C[h,e]); C row = m*16+quad*4+reg
    float s0 = 0.f, s1 = 0.f;
#pragma unroll
    for (int m = 0; m < 8; ++m) {
      float4 wv = *(const float4*)(W_relation + m * 16 + quad * 4);
      s0 += wv.x * elu_f(acc[m][0][0]) + wv.y * elu_f(acc[m][0][1]) +
            wv.z * elu_f(acc[m][0][2]) + wv.w * elu_f(acc[m][0][3]);
      s1 += wv.x * elu_f(acc[m][1][0]) + wv.y * elu_f(acc[m][1][1]) +
            wv.z * elu_f(acc[m][1][2]) + wv.w * elu_f(acc[m][1][3]);
    }
    s0 += __shfl_xor(s0, 16); s0 += __shfl_xor(s0, 32);
    s1 += __shfl_xor(s1, 16); s1 += __shfl_xor(s1, 32);
    if (lane < 32) {
      long e = tile + wave * 32 + lane;
      float sv = (lane & 16) ? s1 : s0;
      int s = src_idx[e], d = dst_idx[e];
      atomicAdd(rel_logits + d, distribution[s] * sv);
    }
  } else {
    // ------------------------------ node path ------------------------------
    const long tile = (long)blockIdx.x * 128;
    const long n0 = tile + r0;
    const long n1 = n0 + 16;
    const bool v0 = n0 < N;
    const bool v1 = n1 < N;
    const float* B0 = node_attrs + n0 * (7 * H_DIM);
    const float* B1 = node_attrs + n1 * (7 * H_DIM);
    const float4 z4 = make_float4(0.f, 0.f, 0.f, 0.f);

    // issue (p=0, ks=0) X loads before first stage
    float4 ca0 = z4, ca1 = z4, cb0 = z4, cb1 = z4;
    if (v0) { ca0 = *(const float4*)(B0 + kq); ca1 = *(const float4*)(B0 + kq + 4); }
    if (v1) { cb0 = *(const float4*)(B1 + kq); cb1 = *(const float4*)(B1 + kq + 4); }

    for (int p = 0; p < 7; ++p) {
      __syncthreads();  // all waves done reading previous slab
      {
        const ushort_t* Wp_h = Wh + p * (H_DIM * H_DIM);
        const ushort_t* Wp_l = Wl + p * (H_DIM * H_DIM);
#pragma unroll
        for (int i = 0; i < 8; ++i) {
          int f = i * 256 + t;
          int row = f >> 4;
          int c8 = (f & 15) * 8;
          *(short8*)&Ah[row * LDS_STRIDE + c8] = *(const short8*)&Wp_h[row * H_DIM + c8];
          *(short8*)&Al[row * LDS_STRIDE + c8] = *(const short8*)&Wp_l[row * H_DIM + c8];
        }
      }
      __syncthreads();

#pragma unroll
      for (int ks = 0; ks < 4; ++ks) {
        float4 na0 = z4, na1 = z4, nb0 = z4, nb1 = z4;
        int np = p, nks = ks + 1;
        if (nks == 4) { np = p + 1; nks = 0; }
        if (np < 7) {  // prefetch next K slice (crosses phase boundary)
          int off = np * H_DIM + nks * 32 + kq;
          if (v0) { na0 = *(const float4*)(B0 + off); na1 = *(const float4*)(B0 + off + 4); }
          if (v1) { nb0 = *(const float4*)(B1 + off); nb1 = *(const float4*)(B1 + off + 4); }
        }
        short8 b0h, b0l, b1h, b1l;
        split8(ca0, ca1, b0h, b0l);
        split8(cb0, cb1, b1h, b1l);
        const int kk = ks * 32 + kq;
#pragma unroll
        for (int m = 0; m < 8; ++m) {
          const int wi = (m * 16 + col) * LDS_STRIDE + kk;
          short8 ah = *(const short8*)&Ah[wi];
          short8 al = *(const short8*)&Al[wi];
          acc[m][0] = __builtin_amdgcn_mfma_f32_16x16x32_bf16(ah, b0h, acc[m][0], 0, 0, 0);
          acc[m][0] = __builtin_amdgcn_mfma_f32_16x16x32_bf16(ah, b0l, acc[m][0], 0, 0, 0);
          acc[m][0] = __builtin_amdgcn_mfma_f32_16x16x32_bf16(al, b0h, acc[m][0], 0, 0, 0);
          acc[m][1] = __builtin_amdgcn_mfma_f32_16x16x32_bf16(ah, b1h, acc[m][1], 0, 0, 0);
          acc[m][1] = __builtin_amdgcn_mfma_f32_16x16x32_bf16(ah, b1l, acc[m][1], 0, 0, 0);
          acc[m][1] = __builtin_amdgcn_mfma_f32_16x16x32_bf16(al, b1h, acc[m][1], 0, 0, 0);
        }
        ca0 = na0; ca1 = na1; cb0 = nb0; cb1 = nb1;
      }
    }

    float s0 = 0.f, s1 = 0.f;
#pragma unroll
    for (int m = 0; m < 8; ++m) {
      float4 wv = *(const float4*)(W_state + m * 16 + quad * 4);
      s0 += wv.x * elu_f(acc[m][0][0]) + wv.y * elu_f(acc[m][0][1]) +
            wv.z * elu_f(acc[m][0][2]) + wv.w * elu_f(acc[m][0][3]);
      s1 += wv.x * elu_f(acc[m][1][0]) + wv.y * elu_f(acc[m][1][1]) +
            wv.z * elu_f(acc[m][1][2]) + wv.w * elu_f(acc[m][1][3]);
    }
    s0 += __shfl_xor(s0, 16); s0 += __shfl_xor(s0, 32);
    s1 += __shfl_xor(s1, 16); s1 += __shfl_xor(s1, 32);
    if (lane < 32) {
      long n = tile + wave * 32 + lane;
      if (n < N) state_logits[n] = (lane & 16) ? s1 : s0;
    }
  }
}

// ---------------------------------------------------------------------------
// Per-graph softmaxes + combine (unchanged — it passed).
__device__ __forceinline__ float wave_red_max(float v) {
#pragma unroll
  for (int off = 32; off > 0; off >>= 1) v = fmaxf(v, __shfl_down(v, off));
  return v;
}
__device__ __forceinline__ float wave_red_sum(float v) {
#pragma unroll
  for (int off = 32; off > 0; off >>= 1) v += __shfl_down(v, off);
  return v;
}

__global__ void finalize_kernel(const float* __restrict__ state_logits,
                                const float* __restrict__ rel_logits,
                                const int* __restrict__ node_graph,
                                const float* __restrict__ prop_sim,
                                float* __restrict__ out, int N) {
  int g = blockIdx.x;
  __shared__ int bounds[2];
  if (threadIdx.x == 0) {
    int a = 0, b = N;
    while (a < b) { int m = (a + b) >> 1; if (node_graph[m] < g) a = m + 1; else b = m; }
    bounds[0] = a;
    b = N;
    while (a < b) { int m = (a + b) >> 1; if (node_graph[m] < g + 1) a = m + 1; else b = m; }
    bounds[1] = a;
  }
  __syncthreads();
  int lo = bounds[0], hi = bounds[1];
  if (lo >= hi) return;

  int lane = threadIdx.x & 63, w = threadIdx.x >> 6;
  __shared__ float redS[4], redR[4];

  float mS = -3.0e38f, mR = -3.0e38f;
  for (int i = lo + threadIdx.x; i < hi; i += blockDim.x) {
    mS = fmaxf(mS, state_logits[i]);
    mR = fmaxf(mR, rel_logits[i]);
  }
  mS = wave_red_max(mS); mR = wave_red_max(mR);
  if (lane == 0) { redS[w] = mS; redR[w] = mR; }
  __syncthreads();
  mS = fmaxf(fmaxf(redS[0], redS[1]), fmaxf(redS[2], redS[3]));
  mR = fmaxf(fmaxf(redR[0], redR[1]), fmaxf(redR[2], redR[3]));
  __syncthreads();

  float sS = 0.f, sR = 0.f;
  for (int i = lo + threadIdx.x; i < hi; i += blockDim.x) {
    sS += expf(state_logits[i] - mS);
    sR += expf(rel_logits[i] - mR);
  }
  sS = wave_red_sum(sS); sR = wave_red_sum(sR);
  if (lane == 0) { redS[w] = sS; redR[w] = sR; }
  __syncthreads();
  sS = redS[0] + redS[1] + redS[2] + redS[3];
  sR = redR[0] + redR[1] + redR[2] + redR[3];

  float p_rel = prop_sim[NPROP - 1];
  float invS = 1.0f / sS, invR = 1.0f / sR;
  for (int i = lo + threadIdx.x; i < hi; i += blockDim.x) {
    float ps = expf(state_logits[i] - mS) * invS;
    float pr = expf(rel_logits[i] - mR) * invR;
    out[i] = p_rel * pr + (1.0f - p_rel) * ps;
  }
}

// ---------------------------------------------------------------------------
extern "C" void kernel_launch(void* const* d_in, const int* in_sizes, int n_in,
                              void* d_out, int out_size, void* d_ws, size_t ws_size,
                              hipStream_t stream) {
  const float* node_attrs   = (const float*)d_in[0];  // [N][7][128]
  const float* edge_attrs   = (const float*)d_in[1];  // [E][128]
  const float* instruction  = (const float*)d_in[2];  // [128]
  const float* prop_embeds  = (const float*)d_in[3];  // [8][128]
  const float* distribution = (const float*)d_in[4];  // [N]
  const float* Ws_property  = (const float*)d_in[5];  // [8][128][128]
  const float* W_state      = (const float*)d_in[6];  // [128]
  const float* W_relation   = (const float*)d_in[7];  // [128]
  const int*   edge_indices = (const int*)d_in[8];    // [2][E]
  const int*   node_graph   = (const int*)d_in[9];    // [N] sorted

  int N = in_sizes[4];
  int E = in_sizes[1] / H_DIM;
  float* out = (float*)d_out;

  // workspace layout (16B-aligned chunks)
  char* w = (char*)d_ws;
  size_t nBytes = ((size_t)N * 4 + 15) & ~(size_t)15;
  float*    prop_sim     = (float*)w;                     // 256 B
  float*    state_logits = (float*)(w + 256);
  float*    rel_logits   = (float*)(w + 256 + nBytes);
  ushort_t* Wh           = (ushort_t*)(w + 256 + 2 * nBytes);
  ushort_t* Wl           = Wh + NPROP * H_DIM * H_DIM;

  hipMemsetAsync(rel_logits, 0, (size_t)N * 4, stream);

  prep_prop_sim<<<1, 512, 0, stream>>>(prop_embeds, instruction, prop_sim);
  prep_weights<<<NPROP * H_DIM * H_DIM / 256, 256, 0, stream>>>(
      Ws_property, instruction, prop_sim, Wh, Wl);

  int nodeBlocks = (N + 127) / 128;   // 391
  int edgeBlocks = E / 128;           // 6250
  fused_mfma_kernel<<<nodeBlocks + edgeBlocks, 256, 0, stream>>>(
      node_attrs, edge_attrs, Wh, Wl, W_state, W_relation,
      distribution, edge_indices, edge_indices + E,
      state_logits, rel_logits, N, nodeBlocks);

  finalize_kernel<<<NGRAPHS, 256, 0, stream>>>(state_logits, rel_logits,
                                               node_graph, prop_sim, out, N);
}